// Round 5
// baseline (562.483 us; speedup 1.0000x reference)
//
#include <hip/hip_runtime.h>

// ResidualAttentionBlock on MI355X (gfx950).
// D=768 H=12 HD=64 NQ=100 KV=257 SEQ=357 BS=32.
// Round 5: 256x256 8-phase GEMM (T2 swizzle + T3/T4 counted vmcnt + T5 setprio + T1 XCD swizzle)
// for qkv/out/fc/proj. nq stays on the 2-phase 128x128 kernel. Attention unchanged.

typedef short bf16x8 __attribute__((ext_vector_type(8)));
typedef float f32x4 __attribute__((ext_vector_type(4)));
typedef unsigned short u16;
typedef unsigned long long u64;

__device__ __forceinline__ u16 f2b(float f) {
    unsigned u = __builtin_bit_cast(unsigned, f);
    u = (u + 0x7fffu + ((u >> 16) & 1u)) >> 16;  // RNE
    return (u16)u;
}
__device__ __forceinline__ float b2f(u16 h) {
    unsigned u = ((unsigned)h) << 16;
    return __builtin_bit_cast(float, u);
}
__device__ __forceinline__ unsigned pack2(float a, float b) {
    return (unsigned)f2b(a) | ((unsigned)f2b(b) << 16);
}
// async global->LDS, 16B per lane; LDS dest = wave-uniform base + lane*16
__device__ __forceinline__ void g2l16(const void* g, void* l) {
    __builtin_amdgcn_global_load_lds(
        (__attribute__((address_space(1))) void*)g,
        (__attribute__((address_space(3))) void*)l, 16, 0, 0);
}
#define MFMA16(a, b, c) __builtin_amdgcn_mfma_f32_16x16x32_bf16((a), (b), (c), 0, 0, 0)
#define BAR() __builtin_amdgcn_s_barrier()
#define SP1() __builtin_amdgcn_s_setprio(1)
#define SP0() __builtin_amdgcn_s_setprio(0)
#define LGK0() do { asm volatile("s_waitcnt lgkmcnt(0)" ::: "memory"); \
                    __builtin_amdgcn_sched_barrier(0); } while (0)
#define VM4()  do { asm volatile("s_waitcnt vmcnt(4)" ::: "memory"); \
                    __builtin_amdgcn_sched_barrier(0); } while (0)

// ---------------- fused f32 -> bf16 conversion of all 5 weights ----------------
__global__ __launch_bounds__(256) void cvt5_kernel(
    const float* __restrict__ s0, const float* __restrict__ s1, const float* __restrict__ s2,
    const float* __restrict__ s3, const float* __restrict__ s4, u16* __restrict__ dst)
{
    int i = blockIdx.x * 256 + threadIdx.x;
    int stride = gridDim.x * 256;
    for (; i < 1916928; i += stride) {
        const float* src; int off;
        if (i < 442368)       { src = s0; off = i; }
        else if (i < 589824)  { src = s1; off = i - 442368; }
        else if (i < 737280)  { src = s2; off = i - 589824; }
        else if (i < 1327104) { src = s3; off = i - 737280; }
        else                  { src = s4; off = i - 1327104; }
        float4 v = ((const float4*)src)[off];
        ushort4 o;
        o.x = f2b(v.x); o.y = f2b(v.y); o.z = f2b(v.z); o.w = f2b(v.w);
        ((ushort4*)dst)[i] = o;
    }
}

// ---------------- mask -> packed bitmask [32*100][5] u64 ----------------
__global__ __launch_bounds__(256) void mask_pack(const int* __restrict__ m, u64* __restrict__ o) {
    int row = blockIdx.x * 4 + (threadIdx.x >> 6);
    int lane = threadIdx.x & 63;
    if (row >= 3200) return;
    const int* r = m + (size_t)row * 257;
    u64 w0 = __ballot(r[lane] != 0);
    u64 w1 = __ballot(r[64 + lane] != 0);
    u64 w2 = __ballot(r[128 + lane] != 0);
    u64 w3 = __ballot(r[192 + lane] != 0);
    u64 w4 = __ballot(lane == 0 && r[256] != 0);
    if (lane == 0) {
        u64* p = o + (size_t)row * 5;
        p[0] = w0; p[1] = w1; p[2] = w2; p[3] = w3; p[4] = w4;
    }
}

// ---------------- LayerNorm (fp32 in, bf16 out), one wave per row of 768 ----------------
__global__ __launch_bounds__(256) void ln_kernel(
    const float* __restrict__ in, const float* __restrict__ g, const float* __restrict__ be,
    u16* __restrict__ out, int nrows)
{
    int row = blockIdx.x * 4 + (threadIdx.x >> 6);
    int lane = threadIdx.x & 63;
    if (row >= nrows) return;
    const float* p = in + (size_t)row * 768;
    float4 a0 = *(const float4*)(p + lane * 4);
    float4 a1 = *(const float4*)(p + 256 + lane * 4);
    float4 a2 = *(const float4*)(p + 512 + lane * 4);
    float s = a0.x + a0.y + a0.z + a0.w + a1.x + a1.y + a1.z + a1.w + a2.x + a2.y + a2.z + a2.w;
    for (int o = 32; o; o >>= 1) s += __shfl_xor(s, o);
    float mean = s * (1.f / 768.f);
    float vs = 0.f;
#define SQA(t) { float dx; dx = t.x-mean; vs += dx*dx; dx = t.y-mean; vs += dx*dx; dx = t.z-mean; vs += dx*dx; dx = t.w-mean; vs += dx*dx; }
    SQA(a0) SQA(a1) SQA(a2)
#undef SQA
    for (int o = 32; o; o >>= 1) vs += __shfl_xor(vs, o);
    float rstd = rsqrtf(vs * (1.f / 768.f) + 1e-5f);
    u16* orow = out + (size_t)row * 768;
#pragma unroll
    for (int i = 0; i < 3; ++i) {
        int d = i * 256 + lane * 4;
        float4 av = (i == 0) ? a0 : ((i == 1) ? a1 : a2);
        float4 gv = *(const float4*)(g + d);
        float4 bv = *(const float4*)(be + d);
        ushort4 ov;
        ov.x = f2b((av.x - mean) * rstd * gv.x + bv.x);
        ov.y = f2b((av.y - mean) * rstd * gv.y + bv.y);
        ov.z = f2b((av.z - mean) * rstd * gv.z + bv.z);
        ov.w = f2b((av.w - mean) * rstd * gv.w + bv.w);
        *(ushort4*)(orow + d) = ov;
    }
}

// ---------------- 2-phase 128x128 GEMM (kept for small shapes: nq) ----------------
template<int ACT, int OUTBF, int RES>
__global__ __launch_bounds__(256) void gemm_bt(
    const u16* __restrict__ A, const u16* __restrict__ B,
    const float* __restrict__ bias, const float* __restrict__ res,
    void* __restrict__ Cp, int M, int N, int K)
{
    __shared__ u16 Al[2][128 * 32];
    __shared__ u16 Bl[2][128 * 32];
    const int t = threadIdx.x;
    const int lane = t & 63, w = t >> 6;
    const int wr = w >> 1, wc = w & 1;
    const int m0 = blockIdx.x * 128, n0 = blockIdx.y * 128;
    const int fr = lane & 15, fg = lane >> 4;

    const int srow = lane >> 2;
    const int scol = (lane & 3) * 8;
    int ar0 = m0 + w * 32 + srow;      int ar1 = ar0 + 16;
    ar0 = ar0 < M ? ar0 : M - 1;       ar1 = ar1 < M ? ar1 : M - 1;
    int br0 = n0 + w * 32 + srow;      int br1 = br0 + 16;
    br0 = br0 < N ? br0 : N - 1;       br1 = br1 < N ? br1 : N - 1;
    const u16* a0p = A + (size_t)ar0 * K + scol;
    const u16* a1p = A + (size_t)ar1 * K + scol;
    const u16* b0p = B + (size_t)br0 * K + scol;
    const u16* b1p = B + (size_t)br1 * K + scol;
    const int lo0 = (w * 2 + 0) * 512, lo1 = (w * 2 + 1) * 512;

    const int nk = K >> 5;
    g2l16(a0p, &Al[0][lo0]);
    g2l16(a1p, &Al[0][lo1]);
    g2l16(b0p, &Bl[0][lo0]);
    g2l16(b1p, &Bl[0][lo1]);
    __syncthreads();

    f32x4 acc[4][4] = {};
#pragma unroll 2
    for (int ki = 0; ki < nk; ++ki) {
        const int cur = ki & 1;
        if (ki + 1 < nk) {
            const int k0 = (ki + 1) << 5;
            const int nxt = cur ^ 1;
            g2l16(a0p + k0, &Al[nxt][lo0]);
            g2l16(a1p + k0, &Al[nxt][lo1]);
            g2l16(b0p + k0, &Bl[nxt][lo0]);
            g2l16(b1p + k0, &Bl[nxt][lo1]);
        }
        bf16x8 af[4], bfr[4];
#pragma unroll
        for (int m = 0; m < 4; ++m) af[m] = *(const bf16x8*)&Al[cur][(wr * 64 + m * 16 + fr) * 32 + fg * 8];
#pragma unroll
        for (int n = 0; n < 4; ++n) bfr[n] = *(const bf16x8*)&Bl[cur][(wc * 64 + n * 16 + fr) * 32 + fg * 8];
#pragma unroll
        for (int m = 0; m < 4; ++m)
#pragma unroll
            for (int n = 0; n < 4; ++n)
                acc[m][n] = MFMA16(af[m], bfr[n], acc[m][n]);
        __syncthreads();
    }
#pragma unroll
    for (int m = 0; m < 4; ++m) {
#pragma unroll
        for (int n = 0; n < 4; ++n) {
            int col = n0 + wc * 64 + n * 16 + fr;
            float bv = bias[col];
#pragma unroll
            for (int r = 0; r < 4; ++r) {
                int row = m0 + wr * 64 + m * 16 + fg * 4 + r;
                if (row < M) {
                    float v = acc[m][n][r] + bv;
                    if (RES) v += res[(size_t)row * N + col];
                    if (ACT) v = v / (1.f + __expf(-1.702f * v));
                    if (OUTBF) ((u16*)Cp)[(size_t)row * N + col] = f2b(v);
                    else       ((float*)Cp)[(size_t)row * N + col] = v;
                }
            }
        }
    }
}

// ---------------- 256x256 8-phase GEMM (T2+T3+T4+T5+T1), BK=64, 8 waves ----------------
// LDS map (bytes): buf b at b*65536; A-half h at +h*16384; B-half h at +32768+h*16384.
// Row r of a half at r*128; 16B slot s at +s*16, swizzled s ^= (r&7) on both write-src and read.
// Requires: N % 256 == 0, K % 128 == 0 (nkt even), K >= 128.
template<int ACT, int OUTBF, int RES>
__global__ __launch_bounds__(512) void gemm256(
    const u16* __restrict__ A, const u16* __restrict__ B,
    const float* __restrict__ bias, const float* __restrict__ res,
    void* __restrict__ Cp, int M, int N, int K)
{
    __shared__ u16 lds[65536];
    const int t = threadIdx.x, lane = t & 63, w = t >> 6;
    const int wr = w >> 2, wc = w & 3;         // wave grid 2M x 4N
    const int fr = lane & 15, fg = lane >> 4;

    // T1: bijective XCD swizzle (m204)
    const int nwg = gridDim.x * gridDim.y;
    int orig = blockIdx.x + gridDim.x * blockIdx.y;
    {
        int q = nwg >> 3, r = nwg & 7;
        int xcd = orig & 7, idx = orig >> 3;
        orig = (xcd < r ? xcd * (q + 1) : r * (q + 1) + (xcd - r) * q) + idx;
    }
    const int m0 = (orig % gridDim.x) * 256;
    const int n0 = (orig / gridDim.x) * 256;

    const int nkt = K >> 6;
    char* ldsB = (char*)lds;
    const int jrow = lane >> 3;                      // 0..7
    const int swz = ((lane & 7) ^ jrow) * 8;         // pre-swizzled source col (elements)

    // stage one 128-row half-tile (2 x g2l16 per wave)
    auto stageA = [&](int b, int h, int kt) {
        int r0 = m0 + h * 128 + w * 16 + jrow;
        int r1 = r0 + 8;
        r0 = r0 < M ? r0 : M - 1;
        r1 = r1 < M ? r1 : M - 1;
        char* lb = ldsB + b * 65536 + h * 16384 + w * 2048;
        g2l16(A + (size_t)r0 * K + kt * 64 + swz, lb);
        g2l16(A + (size_t)r1 * K + kt * 64 + swz, lb + 1024);
    };
    auto stageB = [&](int b, int h, int kt) {
        int r0 = n0 + h * 128 + w * 16 + jrow;       // N % 256 == 0: no clamp
        char* lb = ldsB + b * 65536 + 32768 + h * 16384 + w * 2048;
        g2l16(B + (size_t)r0 * K + kt * 64 + swz, lb);
        g2l16(B + (size_t)(r0 + 8) * K + kt * 64 + swz, lb + 1024);
    };
    // fragment reads (swizzled)
    auto ldA = [&](int b, int mi, int kh) -> bf16x8 {
        int lr = mi * 16 + fr;                       // 0..127 within A-half wr
        int slot = (fg + 4 * kh) ^ (lr & 7);
        return *(const bf16x8*)(ldsB + b * 65536 + wr * 16384 + lr * 128 + slot * 16);
    };
    auto ldB = [&](int b, int ni, int kh) -> bf16x8 {
        int lr = (wc & 1) * 64 + ni * 16 + fr;       // within B-half (wc>>1)
        int slot = (fg + 4 * kh) ^ (lr & 7);
        return *(const bf16x8*)(ldsB + b * 65536 + 32768 + (wc >> 1) * 16384 + lr * 128 + slot * 16);
    };

    f32x4 acc[8][4] = {};

    // prologue: kt0.{B0,B1,A0,A1}, kt1.{B0,B1}; then wait all-but-newest-2 halves + barrier
    stageB(0, 0, 0); stageB(0, 1, 0); stageA(0, 0, 0); stageA(0, 1, 0);
    stageB(1, 0, 1); stageB(1, 1, 1);
    VM4(); BAR();

    // one half-iteration = 4 phases computing K-tile in buf bc; stages A of tile ta -> buf ba,
    // B of tile tb -> buf bb per the derived schedule.
    auto halfiter = [&](int bc, int ba, int ta, int bb, int tb) {
        bf16x8 aa[4][2], bn0[2][2], bn1[2][2];
        // p1: ds A-mh0 (8) + B-nh0 (4); stage ta.A0
#pragma unroll
        for (int mi = 0; mi < 4; ++mi) { aa[mi][0] = ldA(bc, mi, 0); aa[mi][1] = ldA(bc, mi, 1); }
#pragma unroll
        for (int ni = 0; ni < 2; ++ni) { bn0[ni][0] = ldB(bc, ni, 0); bn0[ni][1] = ldB(bc, ni, 1); }
        if (ta < nkt) stageA(ba, 0, ta);
        BAR(); LGK0(); SP1();
#pragma unroll
        for (int mi = 0; mi < 4; ++mi)
#pragma unroll
            for (int ni = 0; ni < 2; ++ni) {
                acc[mi][ni] = MFMA16(aa[mi][0], bn0[ni][0], acc[mi][ni]);
                acc[mi][ni] = MFMA16(aa[mi][1], bn0[ni][1], acc[mi][ni]);
            }
        SP0(); BAR();
        // p2: ds B-nh1 (4); stage ta.A1
#pragma unroll
        for (int ni = 0; ni < 2; ++ni) { bn1[ni][0] = ldB(bc, 2 + ni, 0); bn1[ni][1] = ldB(bc, 2 + ni, 1); }
        if (ta < nkt) stageA(ba, 1, ta);
        BAR(); LGK0(); SP1();
#pragma unroll
        for (int mi = 0; mi < 4; ++mi)
#pragma unroll
            for (int ni = 0; ni < 2; ++ni) {
                acc[mi][2 + ni] = MFMA16(aa[mi][0], bn1[ni][0], acc[mi][2 + ni]);
                acc[mi][2 + ni] = MFMA16(aa[mi][1], bn1[ni][1], acc[mi][2 + ni]);
            }
        SP0(); BAR();
        // p3: ds A-mh1 (8); stage tb.B0
#pragma unroll
        for (int mi = 0; mi < 4; ++mi) { aa[mi][0] = ldA(bc, 4 + mi, 0); aa[mi][1] = ldA(bc, 4 + mi, 1); }
        if (tb < nkt) stageB(bb, 0, tb);
        BAR(); LGK0(); SP1();
#pragma unroll
        for (int mi = 0; mi < 4; ++mi)
#pragma unroll
            for (int ni = 0; ni < 2; ++ni) {
                acc[4 + mi][ni] = MFMA16(aa[mi][0], bn0[ni][0], acc[4 + mi][ni]);
                acc[4 + mi][ni] = MFMA16(aa[mi][1], bn0[ni][1], acc[4 + mi][ni]);
            }
        SP0(); BAR();
        // p4: stage tb.B1; MFMA quad (mh1,nh1); counted vmcnt before closing barrier
        if (tb < nkt) stageB(bb, 1, tb);
        BAR(); SP1();
#pragma unroll
        for (int mi = 0; mi < 4; ++mi)
#pragma unroll
            for (int ni = 0; ni < 2; ++ni) {
                acc[4 + mi][2 + ni] = MFMA16(aa[mi][0], bn1[ni][0], acc[4 + mi][2 + ni]);
                acc[4 + mi][2 + ni] = MFMA16(aa[mi][1], bn1[ni][1], acc[4 + mi][2 + ni]);
            }
        SP0(); VM4(); BAR();
    };

    for (int i = 0; i < nkt; i += 2) {
        halfiter(0, 1, i + 1, 0, i + 2);
        halfiter(1, 0, i + 2, 1, i + 3);
    }

    // epilogue: C/D layout col = fr (within n-frag), row = fg*4 + rr (within m-frag)
#pragma unroll
    for (int mi = 0; mi < 8; ++mi) {
#pragma unroll
        for (int ni = 0; ni < 4; ++ni) {
            int col = n0 + wc * 64 + ni * 16 + fr;
            float bv = bias[col];
#pragma unroll
            for (int rr = 0; rr < 4; ++rr) {
                int row = m0 + wr * 128 + mi * 16 + fg * 4 + rr;
                if (row < M) {
                    float v = acc[mi][ni][rr] + bv;
                    if (RES) v += res[(size_t)row * N + col];
                    if (ACT) v = v / (1.f + __expf(-1.702f * v));
                    if (OUTBF) ((u16*)Cp)[(size_t)row * N + col] = f2b(v);
                    else       ((float*)Cp)[(size_t)row * N + col] = v;
                }
            }
        }
    }
}

// ---------------- MFMA attention: one block per (b,h) ----------------
__global__ __launch_bounds__(256, 2) void attn_kernel(
    const u16* __restrict__ qkv,   // [257*32][2304] rows m*32+b; q|k|v at +0/+768/+1536
    const u16* __restrict__ nq,    // [100*32][768]  rows q*32+b
    const u64* __restrict__ mpk,   // [32*100][5] packed mask bits (1 = blocked)
    u16* __restrict__ out)         // [357*32][768]  rows q*32+b
{
    __shared__ u16 Kl[272 * 64];   // K rows, XOR-swizzled: byte ^= (row&7)<<4
    __shared__ u16 Vt[64 * 296];   // Vt[d][m], row stride 592B
    __shared__ u16 Pb[4][640];     // per-wave P chunk buffer [16][40]
    const int bid = blockIdx.x;
    const int b = bid / 12, h = bid % 12;
    const int t = threadIdx.x, lane = t & 63, wv = t >> 6;
    const int fr = lane & 15, fg = lane >> 4;

    for (int i = t; i < 2048; i += 256) {
        int d = i >> 5, c = 257 + (i & 31);
        if (c < 288) Vt[d * 296 + c] = 0;
    }
    {
        const int r8 = t >> 3, c8 = (t & 7) * 8;
        const u16* kb = qkv + 768 + h * 64 + c8;
        const u16* vb = qkv + 1536 + h * 64 + c8;
#pragma unroll 1
        for (int p = 0; p < 9; ++p) {
            int m = r8 + p * 32;
            if (m <= 256) {
                size_t go = (size_t)(m * 32 + b) * 2304;
                bf16x8 kv = *(const bf16x8*)(kb + go);
                int byte = m * 128 + c8 * 2;
                *(bf16x8*)((char*)Kl + (byte ^ ((m & 7) << 4))) = kv;
                bf16x8 vv = *(const bf16x8*)(vb + go);
#pragma unroll
                for (int j = 0; j < 8; ++j)
                    Vt[(c8 + j) * 296 + m] = (u16)vv[j];
            }
        }
    }
    __syncthreads();

    const int swzK = (fr & 7) << 4;
    char* pb = (char*)&Pb[wv][0];
    const char* KlB = (const char*)Kl;
    const char* VtB = (const char*)Vt;

    auto fetch = [&](int ti, bf16x8& q0v, bf16x8& q1v, u64* mw, bool& im) {
        int q = ti * 16 + fr;
        int qc = q < 357 ? q : 356;
        im = qc < 100;
        const u16* qp = im ? (nq + (size_t)(qc * 32 + b) * 768 + h * 64)
                           : (qkv + (size_t)((qc - 100) * 32 + b) * 2304 + h * 64);
        q0v = *(const bf16x8*)(qp + fg * 8);
        q1v = *(const bf16x8*)(qp + 32 + fg * 8);
        if (im) {
            const u64* mp = mpk + (size_t)(b * 100 + qc) * 5;
            mw[0] = mp[0]; mw[1] = mp[1]; mw[2] = mp[2]; mw[3] = mp[3]; mw[4] = mp[4];
        } else {
            mw[0] = mw[1] = mw[2] = mw[3] = mw[4] = 0;
        }
    };

    bf16x8 qf0, qf1, qn0, qn1;
    u64 mwc[5], mwn[5];
    bool imc, imn;
    fetch(wv, qf0, qf1, mwc, imc);

#pragma unroll 1
    for (int ti = wv; ti < 23; ti += 4) {
        f32x4 sc[17];
#pragma unroll
        for (int kt = 0; kt < 17; ++kt) {
            int rb = (kt * 16 + fr) * 128;
            bf16x8 ka0 = *(const bf16x8*)(KlB + ((rb + fg * 16) ^ swzK));
            bf16x8 ka1 = *(const bf16x8*)(KlB + ((rb + 64 + fg * 16) ^ swzK));
            f32x4 a = {0.f, 0.f, 0.f, 0.f};
            a = MFMA16(ka0, qf0, a);
            a = MFMA16(ka1, qf1, a);
            sc[kt] = a;
        }
        if (ti + 4 < 23) fetch(ti + 4, qn0, qn1, mwn, imn);
        float mx = -INFINITY;
#pragma unroll
        for (int kt = 0; kt < 17; ++kt) {
            u64 mw = (kt >> 2) == 0 ? mwc[0] : (kt >> 2) == 1 ? mwc[1] : (kt >> 2) == 2 ? mwc[2]
                   : (kt >> 2) == 3 ? mwc[3] : mwc[4];
#pragma unroll
            for (int r = 0; r < 4; ++r) {
                int key = kt * 16 + fg * 4 + r;
                bool bad = (key > 256) || (imc && ((mw >> (key & 63)) & 1ull));
                float s = bad ? -INFINITY : sc[kt][r];
                sc[kt][r] = s;
                mx = fmaxf(mx, s);
            }
        }
        mx = fmaxf(mx, __shfl_xor(mx, 16));
        mx = fmaxf(mx, __shfl_xor(mx, 32));
        float l = 0.f;
        unsigned pk[17][2];
#pragma unroll
        for (int kt = 0; kt < 17; ++kt) {
            float p0 = __expf((sc[kt][0] - mx) * 0.125f);
            float p1 = __expf((sc[kt][1] - mx) * 0.125f);
            float p2 = __expf((sc[kt][2] - mx) * 0.125f);
            float p3 = __expf((sc[kt][3] - mx) * 0.125f);
            l += (p0 + p1) + (p2 + p3);
            pk[kt][0] = pack2(p0, p1);
            pk[kt][1] = pack2(p2, p3);
        }
        l += __shfl_xor(l, 16);
        l += __shfl_xor(l, 32);
        f32x4 oc[4] = {};
#pragma unroll
        for (int c = 0; c < 9; ++c) {
            uint2 w0; w0.x = pk[2 * c][0]; w0.y = pk[2 * c][1];
            *(uint2*)(pb + fr * 80 + fg * 8) = w0;
            uint2 w1;
            if (c < 8) { w1.x = pk[2 * c + 1][0]; w1.y = pk[2 * c + 1][1]; }
            else       { w1.x = 0; w1.y = 0; }
            *(uint2*)(pb + fr * 80 + 32 + fg * 8) = w1;
            bf16x8 pf = *(const bf16x8*)(pb + fr * 80 + fg * 16);
#pragma unroll
            for (int dt = 0; dt < 4; ++dt) {
                bf16x8 vf = *(const bf16x8*)(VtB + (dt * 16 + fr) * 592 + c * 64 + fg * 16);
                oc[dt] = MFMA16(vf, pf, oc[dt]);
            }
        }
        int q = ti * 16 + fr;
        if (q < 357) {
            float rl = 1.f / l;
            u16* op = out + (size_t)(q * 32 + b) * 768 + h * 64 + fg * 4;
#pragma unroll
            for (int dt = 0; dt < 4; ++dt) {
                ushort4 ov;
                ov.x = f2b(oc[dt][0] * rl); ov.y = f2b(oc[dt][1] * rl);
                ov.z = f2b(oc[dt][2] * rl); ov.w = f2b(oc[dt][3] * rl);
                *(ushort4*)(op + dt * 16) = ov;
            }
        }
        if (ti + 4 < 23) {
            qf0 = qn0; qf1 = qn1; imc = imn;
            mwc[0] = mwn[0]; mwc[1] = mwn[1]; mwc[2] = mwn[2]; mwc[3] = mwn[3]; mwc[4] = mwn[4];
        }
    }
}

// ---------------- launch ----------------
extern "C" void kernel_launch(void* const* d_in, const int* in_sizes, int n_in,
                              void* d_out, int out_size, void* d_ws, size_t ws_size,
                              hipStream_t stream)
{
    const float* y   = (const float*)d_in[0];
    const int*   msk = (const int*)  d_in[1];
    const float* ipw = (const float*)d_in[2];
    const float* ipb = (const float*)d_in[3];
    const float* nqw = (const float*)d_in[4];
    const float* nqb = (const float*)d_in[5];
    const float* ow  = (const float*)d_in[6];
    const float* ob  = (const float*)d_in[7];
    const float* l1g = (const float*)d_in[8];
    const float* l1b = (const float*)d_in[9];
    const float* l2g = (const float*)d_in[10];
    const float* l2b = (const float*)d_in[11];
    const float* fcw = (const float*)d_in[12];
    const float* fcb = (const float*)d_in[13];
    const float* pjw = (const float*)d_in[14];
    const float* pjb = (const float*)d_in[15];

    char* ws = (char*)d_ws;
    u16* x_b   = (u16*)(ws + 0);          // 11424 x 768
    u16* qkv_b = (u16*)(ws + 17547264);   //  8224 x 2304
    u16* nq_b  = (u16*)(ws + 55443456);   //  3200 x 768
    u16* ao_b  = (u16*)(ws + 60358656);   // 11424 x 768
    u16* h1_b  = (u16*)(ws + 0);          // 11424 x 3072 (phase 2, overlaps phase-1 region)
    u16* h_b   = (u16*)(ws + 77905920);   // 11424 x 768 (phase 2)
    u64* mpk_b = (u64*)(ws + 77905920);   // 3200 x 5 u64 (phase 1 only)
    u16* w_ip  = (u16*)(ws + 95453184);   // weights contiguous: ip|nq|out|fc|pj
    float* out = (float*)d_out;

    cvt5_kernel<<<2048, 256, 0, stream>>>(ipw, nqw, ow, fcw, pjw, w_ip);
    mask_pack<<<800, 256, 0, stream>>>(msk, mpk_b);

    u16* w_nq  = w_ip + 1769472;
    u16* w_out = w_nq + 589824;
    u16* w_fc  = w_out + 589824;
    u16* w_pj  = w_fc + 2359296;

    // x = LN1(y) -> bf16
    ln_kernel<<<2856, 256, 0, stream>>>(y, l1g, l1b, x_b, 11424);
    // qkv = x[100:] @ in_proj_w.T + b   (M=8224, N=2304, K=768)
    gemm256<0, 1, 0><<<dim3(33, 9), 512, 0, stream>>>(x_b + (size_t)3200 * 768, w_ip, ipb, nullptr, qkv_b, 8224, 2304, 768);
    // new_q = x[:100] @ new_q_w.T + b   (small: keep 2-phase)
    gemm_bt<0, 1, 0><<<dim3(25, 6), 256, 0, stream>>>(x_b, w_nq, nqb, nullptr, nq_b, 3200, 768, 768);
    // attention
    attn_kernel<<<384, 256, 0, stream>>>(qkv_b, nq_b, mpk_b, ao_b);
    // y2 = y + attn_out @ out_w.T + out_b   -> d_out (f32)
    gemm256<0, 0, 1><<<dim3(45, 3), 512, 0, stream>>>(ao_b, w_out, ob, y, out, 11424, 768, 768);
    // h = LN2(y2) -> bf16
    ln_kernel<<<2856, 256, 0, stream>>>(out, l2g, l2b, h_b, 11424);
    // h1 = quickgelu(h @ fc_w.T + fc_b) -> bf16
    gemm256<1, 1, 0><<<dim3(45, 12), 512, 0, stream>>>(h_b, w_fc, fcb, nullptr, h1_b, 11424, 3072, 768);
    // out = y2 + h1 @ proj_w.T + proj_b
    gemm256<0, 0, 1><<<dim3(45, 3), 512, 0, stream>>>(h1_b, w_pj, pjb, out, out, 11424, 768, 3072);
}

// Round 6
// 490.469 us; speedup vs baseline: 1.1468x; 1.1468x over previous
//
#include <hip/hip_runtime.h>

// ResidualAttentionBlock on MI355X (gfx950).
// D=768 H=12 HD=64 NQ=100 KV=257 SEQ=357 BS=32.
// Round 6: 128x128 GEMM with 3-buffer LDS pipeline, prefetch distance 2, counted vmcnt(4)
// + raw s_barrier (T4 at 128² granularity — keeps grid fit, removes the vmcnt(0) drain).

typedef short bf16x8 __attribute__((ext_vector_type(8)));
typedef float f32x4 __attribute__((ext_vector_type(4)));
typedef unsigned short u16;
typedef unsigned long long u64;

__device__ __forceinline__ u16 f2b(float f) {
    unsigned u = __builtin_bit_cast(unsigned, f);
    u = (u + 0x7fffu + ((u >> 16) & 1u)) >> 16;  // RNE
    return (u16)u;
}
__device__ __forceinline__ float b2f(u16 h) {
    unsigned u = ((unsigned)h) << 16;
    return __builtin_bit_cast(float, u);
}
__device__ __forceinline__ unsigned pack2(float a, float b) {
    return (unsigned)f2b(a) | ((unsigned)f2b(b) << 16);
}
// async global->LDS, 16B per lane; LDS dest = wave-uniform base + lane*16
__device__ __forceinline__ void g2l16(const void* g, void* l) {
    __builtin_amdgcn_global_load_lds(
        (__attribute__((address_space(1))) void*)g,
        (__attribute__((address_space(3))) void*)l, 16, 0, 0);
}
#define MFMA16(a, b, c) __builtin_amdgcn_mfma_f32_16x16x32_bf16((a), (b), (c), 0, 0, 0)
#define BAR() __builtin_amdgcn_s_barrier()
#define VM4() do { asm volatile("s_waitcnt vmcnt(4)" ::: "memory"); \
                   __builtin_amdgcn_sched_barrier(0); } while (0)
#define VM0() do { asm volatile("s_waitcnt vmcnt(0)" ::: "memory"); \
                   __builtin_amdgcn_sched_barrier(0); } while (0)

// ---------------- fused f32 -> bf16 conversion of all 5 weights ----------------
__global__ __launch_bounds__(256) void cvt5_kernel(
    const float* __restrict__ s0, const float* __restrict__ s1, const float* __restrict__ s2,
    const float* __restrict__ s3, const float* __restrict__ s4, u16* __restrict__ dst)
{
    int i = blockIdx.x * 256 + threadIdx.x;
    int stride = gridDim.x * 256;
    for (; i < 1916928; i += stride) {
        const float* src; int off;
        if (i < 442368)       { src = s0; off = i; }
        else if (i < 589824)  { src = s1; off = i - 442368; }
        else if (i < 737280)  { src = s2; off = i - 589824; }
        else if (i < 1327104) { src = s3; off = i - 737280; }
        else                  { src = s4; off = i - 1327104; }
        float4 v = ((const float4*)src)[off];
        ushort4 o;
        o.x = f2b(v.x); o.y = f2b(v.y); o.z = f2b(v.z); o.w = f2b(v.w);
        ((ushort4*)dst)[i] = o;
    }
}

// ---------------- mask -> packed bitmask [32*100][5] u64 ----------------
__global__ __launch_bounds__(256) void mask_pack(const int* __restrict__ m, u64* __restrict__ o) {
    int row = blockIdx.x * 4 + (threadIdx.x >> 6);
    int lane = threadIdx.x & 63;
    if (row >= 3200) return;
    const int* r = m + (size_t)row * 257;
    u64 w0 = __ballot(r[lane] != 0);
    u64 w1 = __ballot(r[64 + lane] != 0);
    u64 w2 = __ballot(r[128 + lane] != 0);
    u64 w3 = __ballot(r[192 + lane] != 0);
    u64 w4 = __ballot(lane == 0 && r[256] != 0);
    if (lane == 0) {
        u64* p = o + (size_t)row * 5;
        p[0] = w0; p[1] = w1; p[2] = w2; p[3] = w3; p[4] = w4;
    }
}

// ---------------- LayerNorm (fp32 in, bf16 out), one wave per row of 768 ----------------
__global__ __launch_bounds__(256) void ln_kernel(
    const float* __restrict__ in, const float* __restrict__ g, const float* __restrict__ be,
    u16* __restrict__ out, int nrows)
{
    int row = blockIdx.x * 4 + (threadIdx.x >> 6);
    int lane = threadIdx.x & 63;
    if (row >= nrows) return;
    const float* p = in + (size_t)row * 768;
    float4 a0 = *(const float4*)(p + lane * 4);
    float4 a1 = *(const float4*)(p + 256 + lane * 4);
    float4 a2 = *(const float4*)(p + 512 + lane * 4);
    float s = a0.x + a0.y + a0.z + a0.w + a1.x + a1.y + a1.z + a1.w + a2.x + a2.y + a2.z + a2.w;
    for (int o = 32; o; o >>= 1) s += __shfl_xor(s, o);
    float mean = s * (1.f / 768.f);
    float vs = 0.f;
#define SQA(t) { float dx; dx = t.x-mean; vs += dx*dx; dx = t.y-mean; vs += dx*dx; dx = t.z-mean; vs += dx*dx; dx = t.w-mean; vs += dx*dx; }
    SQA(a0) SQA(a1) SQA(a2)
#undef SQA
    for (int o = 32; o; o >>= 1) vs += __shfl_xor(vs, o);
    float rstd = rsqrtf(vs * (1.f / 768.f) + 1e-5f);
    u16* orow = out + (size_t)row * 768;
#pragma unroll
    for (int i = 0; i < 3; ++i) {
        int d = i * 256 + lane * 4;
        float4 av = (i == 0) ? a0 : ((i == 1) ? a1 : a2);
        float4 gv = *(const float4*)(g + d);
        float4 bv = *(const float4*)(be + d);
        ushort4 ov;
        ov.x = f2b((av.x - mean) * rstd * gv.x + bv.x);
        ov.y = f2b((av.y - mean) * rstd * gv.y + bv.y);
        ov.z = f2b((av.z - mean) * rstd * gv.z + bv.z);
        ov.w = f2b((av.w - mean) * rstd * gv.w + bv.w);
        *(ushort4*)(orow + d) = ov;
    }
}

// ---------------- bf16 MFMA GEMM: C[M][N] = A[M][K] @ B[N][K]^T + bias (+res) ----------------
// 128x128 tile, 4 waves (2x2), 4x4 16x16 frags/wave, BK=32.
// 3 LDS buffers, prefetch distance 2, counted vmcnt(4): tile ki+2's loads stay in flight
// across the barrier; only tile ki+1's (issued one step earlier) are waited.
template<int ACT, int OUTBF, int RES>
__global__ __launch_bounds__(256) void gemm_bt(
    const u16* __restrict__ A, const u16* __restrict__ B,
    const float* __restrict__ bias, const float* __restrict__ res,
    void* __restrict__ Cp, int M, int N, int K)
{
    __shared__ u16 Al[3][128 * 32];
    __shared__ u16 Bl[3][128 * 32];
    const int t = threadIdx.x;
    const int lane = t & 63, w = t >> 6;
    const int wr = w >> 1, wc = w & 1;
    const int m0 = blockIdx.x * 128, n0 = blockIdx.y * 128;
    const int fr = lane & 15, fg = lane >> 4;

    // staging: wave w covers rows w*32..w*32+31 (2 instrs of 16 rows); lane l -> row +(l>>2),
    // 16B slot (l&3). LDS dest is wave-uniform base + lane*16; global src per-lane (row-clamped).
    const int srow = lane >> 2;
    const int scol = (lane & 3) * 8;
    int ar0 = m0 + w * 32 + srow;      int ar1 = ar0 + 16;
    ar0 = ar0 < M ? ar0 : M - 1;       ar1 = ar1 < M ? ar1 : M - 1;
    int br0 = n0 + w * 32 + srow;      int br1 = br0 + 16;
    br0 = br0 < N ? br0 : N - 1;       br1 = br1 < N ? br1 : N - 1;
    const u16* a0p = A + (size_t)ar0 * K + scol;
    const u16* a1p = A + (size_t)ar1 * K + scol;
    const u16* b0p = B + (size_t)br0 * K + scol;
    const u16* b1p = B + (size_t)br1 * K + scol;
    const int lo0 = (w * 2 + 0) * 512, lo1 = (w * 2 + 1) * 512;

    const int nk = K >> 5;
    auto stage = [&](int ki, int bsel) {
        const int k0 = ki << 5;
        g2l16(a0p + k0, &Al[bsel][lo0]);
        g2l16(a1p + k0, &Al[bsel][lo1]);
        g2l16(b0p + k0, &Bl[bsel][lo0]);
        g2l16(b1p + k0, &Bl[bsel][lo1]);
    };
    // prologue: stage tiles 0 and 1; wait tile 0 (oldest 4 of 8 outstanding)
    stage(0, 0);
    stage(1, 1);
    VM4();
    BAR();

    f32x4 acc[4][4] = {};
#pragma unroll 3
    for (int ki = 0; ki < nk; ++ki) {
        const int cur = ki % 3;
        if (ki + 2 < nk) stage(ki + 2, (ki + 2) % 3);   // issue-early: 2 tiles ahead
        bf16x8 af[4], bfr[4];
#pragma unroll
        for (int m = 0; m < 4; ++m) af[m] = *(const bf16x8*)&Al[cur][(wr * 64 + m * 16 + fr) * 32 + fg * 8];
#pragma unroll
        for (int n = 0; n < 4; ++n) bfr[n] = *(const bf16x8*)&Bl[cur][(wc * 64 + n * 16 + fr) * 32 + fg * 8];
#pragma unroll
        for (int m = 0; m < 4; ++m)
#pragma unroll
            for (int n = 0; n < 4; ++n)
                acc[m][n] = MFMA16(af[m], bfr[n], acc[m][n]);
        if (ki + 1 < nk) {
            if (ki + 2 < nk) { VM4(); } else { VM0(); }  // wait ONLY tile ki+1's loads
            BAR();
        }
    }
    // Epilogue. C/D layout: col = lane&15, row = (lane>>4)*4 + r  [measured m89/m91]
#pragma unroll
    for (int m = 0; m < 4; ++m) {
#pragma unroll
        for (int n = 0; n < 4; ++n) {
            int col = n0 + wc * 64 + n * 16 + fr;
            float bv = bias[col];
#pragma unroll
            for (int r = 0; r < 4; ++r) {
                int row = m0 + wr * 64 + m * 16 + fg * 4 + r;
                if (row < M) {
                    float v = acc[m][n][r] + bv;
                    if (RES) v += res[(size_t)row * N + col];
                    if (ACT) v = v / (1.f + __expf(-1.702f * v));  // QuickGELU
                    if (OUTBF) ((u16*)Cp)[(size_t)row * N + col] = f2b(v);
                    else       ((float*)Cp)[(size_t)row * N + col] = v;
                }
            }
        }
    }
}

// ---------------- MFMA attention: one block per (b,h) ----------------
__global__ __launch_bounds__(256, 2) void attn_kernel(
    const u16* __restrict__ qkv,   // [257*32][2304] rows m*32+b; q|k|v at +0/+768/+1536
    const u16* __restrict__ nq,    // [100*32][768]  rows q*32+b
    const u64* __restrict__ mpk,   // [32*100][5] packed mask bits (1 = blocked)
    u16* __restrict__ out)         // [357*32][768]  rows q*32+b
{
    __shared__ u16 Kl[272 * 64];   // K rows, XOR-swizzled: byte ^= (row&7)<<4
    __shared__ u16 Vt[64 * 296];   // Vt[d][m], row stride 592B
    __shared__ u16 Pb[4][640];     // per-wave P chunk buffer [16][40]
    const int bid = blockIdx.x;
    const int b = bid / 12, h = bid % 12;
    const int t = threadIdx.x, lane = t & 63, wv = t >> 6;
    const int fr = lane & 15, fg = lane >> 4;

    for (int i = t; i < 2048; i += 256) {
        int d = i >> 5, c = 257 + (i & 31);
        if (c < 288) Vt[d * 296 + c] = 0;
    }
    {
        const int r8 = t >> 3, c8 = (t & 7) * 8;
        const u16* kb = qkv + 768 + h * 64 + c8;
        const u16* vb = qkv + 1536 + h * 64 + c8;
#pragma unroll 1
        for (int p = 0; p < 9; ++p) {
            int m = r8 + p * 32;
            if (m <= 256) {
                size_t go = (size_t)(m * 32 + b) * 2304;
                bf16x8 kv = *(const bf16x8*)(kb + go);
                int byte = m * 128 + c8 * 2;
                *(bf16x8*)((char*)Kl + (byte ^ ((m & 7) << 4))) = kv;
                bf16x8 vv = *(const bf16x8*)(vb + go);
#pragma unroll
                for (int j = 0; j < 8; ++j)
                    Vt[(c8 + j) * 296 + m] = (u16)vv[j];
            }
        }
    }
    __syncthreads();

    const int swzK = (fr & 7) << 4;
    char* pb = (char*)&Pb[wv][0];
    const char* KlB = (const char*)Kl;
    const char* VtB = (const char*)Vt;

    auto fetch = [&](int ti, bf16x8& q0v, bf16x8& q1v, u64* mw, bool& im) {
        int q = ti * 16 + fr;
        int qc = q < 357 ? q : 356;
        im = qc < 100;
        const u16* qp = im ? (nq + (size_t)(qc * 32 + b) * 768 + h * 64)
                           : (qkv + (size_t)((qc - 100) * 32 + b) * 2304 + h * 64);
        q0v = *(const bf16x8*)(qp + fg * 8);
        q1v = *(const bf16x8*)(qp + 32 + fg * 8);
        if (im) {
            const u64* mp = mpk + (size_t)(b * 100 + qc) * 5;
            mw[0] = mp[0]; mw[1] = mp[1]; mw[2] = mp[2]; mw[3] = mp[3]; mw[4] = mp[4];
        } else {
            mw[0] = mw[1] = mw[2] = mw[3] = mw[4] = 0;
        }
    };

    bf16x8 qf0, qf1, qn0, qn1;
    u64 mwc[5], mwn[5];
    bool imc, imn;
    fetch(wv, qf0, qf1, mwc, imc);

#pragma unroll 1
    for (int ti = wv; ti < 23; ti += 4) {
        f32x4 sc[17];
#pragma unroll
        for (int kt = 0; kt < 17; ++kt) {
            int rb = (kt * 16 + fr) * 128;
            bf16x8 ka0 = *(const bf16x8*)(KlB + ((rb + fg * 16) ^ swzK));
            bf16x8 ka1 = *(const bf16x8*)(KlB + ((rb + 64 + fg * 16) ^ swzK));
            f32x4 a = {0.f, 0.f, 0.f, 0.f};
            a = MFMA16(ka0, qf0, a);
            a = MFMA16(ka1, qf1, a);
            sc[kt] = a;
        }
        if (ti + 4 < 23) fetch(ti + 4, qn0, qn1, mwn, imn);
        float mx = -INFINITY;
#pragma unroll
        for (int kt = 0; kt < 17; ++kt) {
            u64 mw = (kt >> 2) == 0 ? mwc[0] : (kt >> 2) == 1 ? mwc[1] : (kt >> 2) == 2 ? mwc[2]
                   : (kt >> 2) == 3 ? mwc[3] : mwc[4];
#pragma unroll
            for (int r = 0; r < 4; ++r) {
                int key = kt * 16 + fg * 4 + r;
                bool bad = (key > 256) || (imc && ((mw >> (key & 63)) & 1ull));
                float s = bad ? -INFINITY : sc[kt][r];
                sc[kt][r] = s;
                mx = fmaxf(mx, s);
            }
        }
        mx = fmaxf(mx, __shfl_xor(mx, 16));
        mx = fmaxf(mx, __shfl_xor(mx, 32));
        float l = 0.f;
        unsigned pk[17][2];
#pragma unroll
        for (int kt = 0; kt < 17; ++kt) {
            float p0 = __expf((sc[kt][0] - mx) * 0.125f);
            float p1 = __expf((sc[kt][1] - mx) * 0.125f);
            float p2 = __expf((sc[kt][2] - mx) * 0.125f);
            float p3 = __expf((sc[kt][3] - mx) * 0.125f);
            l += (p0 + p1) + (p2 + p3);
            pk[kt][0] = pack2(p0, p1);
            pk[kt][1] = pack2(p2, p3);
        }
        l += __shfl_xor(l, 16);
        l += __shfl_xor(l, 32);
        f32x4 oc[4] = {};
#pragma unroll
        for (int c = 0; c < 9; ++c) {
            uint2 w0; w0.x = pk[2 * c][0]; w0.y = pk[2 * c][1];
            *(uint2*)(pb + fr * 80 + fg * 8) = w0;
            uint2 w1;
            if (c < 8) { w1.x = pk[2 * c + 1][0]; w1.y = pk[2 * c + 1][1]; }
            else       { w1.x = 0; w1.y = 0; }
            *(uint2*)(pb + fr * 80 + 32 + fg * 8) = w1;
            bf16x8 pf = *(const bf16x8*)(pb + fr * 80 + fg * 16);
#pragma unroll
            for (int dt = 0; dt < 4; ++dt) {
                bf16x8 vf = *(const bf16x8*)(VtB + (dt * 16 + fr) * 592 + c * 64 + fg * 16);
                oc[dt] = MFMA16(vf, pf, oc[dt]);
            }
        }
        int q = ti * 16 + fr;
        if (q < 357) {
            float rl = 1.f / l;
            u16* op = out + (size_t)(q * 32 + b) * 768 + h * 64 + fg * 4;
#pragma unroll
            for (int dt = 0; dt < 4; ++dt) {
                ushort4 ov;
                ov.x = f2b(oc[dt][0] * rl); ov.y = f2b(oc[dt][1] * rl);
                ov.z = f2b(oc[dt][2] * rl); ov.w = f2b(oc[dt][3] * rl);
                *(ushort4*)(op + dt * 16) = ov;
            }
        }
        if (ti + 4 < 23) {
            qf0 = qn0; qf1 = qn1; imc = imn;
            mwc[0] = mwn[0]; mwc[1] = mwn[1]; mwc[2] = mwn[2]; mwc[3] = mwn[3]; mwc[4] = mwn[4];
        }
    }
}

// ---------------- launch ----------------
extern "C" void kernel_launch(void* const* d_in, const int* in_sizes, int n_in,
                              void* d_out, int out_size, void* d_ws, size_t ws_size,
                              hipStream_t stream)
{
    const float* y   = (const float*)d_in[0];
    const int*   msk = (const int*)  d_in[1];
    const float* ipw = (const float*)d_in[2];
    const float* ipb = (const float*)d_in[3];
    const float* nqw = (const float*)d_in[4];
    const float* nqb = (const float*)d_in[5];
    const float* ow  = (const float*)d_in[6];
    const float* ob  = (const float*)d_in[7];
    const float* l1g = (const float*)d_in[8];
    const float* l1b = (const float*)d_in[9];
    const float* l2g = (const float*)d_in[10];
    const float* l2b = (const float*)d_in[11];
    const float* fcw = (const float*)d_in[12];
    const float* fcb = (const float*)d_in[13];
    const float* pjw = (const float*)d_in[14];
    const float* pjb = (const float*)d_in[15];

    char* ws = (char*)d_ws;
    u16* x_b   = (u16*)(ws + 0);          // 11424 x 768
    u16* qkv_b = (u16*)(ws + 17547264);   //  8224 x 2304
    u16* nq_b  = (u16*)(ws + 55443456);   //  3200 x 768
    u16* ao_b  = (u16*)(ws + 60358656);   // 11424 x 768
    u16* h1_b  = (u16*)(ws + 0);          // 11424 x 3072 (phase 2, overlaps phase-1 region)
    u16* h_b   = (u16*)(ws + 77905920);   // 11424 x 768 (phase 2)
    u64* mpk_b = (u64*)(ws + 77905920);   // 3200 x 5 u64 (phase 1 only)
    u16* w_ip  = (u16*)(ws + 95453184);   // weights contiguous: ip|nq|out|fc|pj
    float* out = (float*)d_out;

    cvt5_kernel<<<2048, 256, 0, stream>>>(ipw, nqw, ow, fcw, pjw, w_ip);
    mask_pack<<<800, 256, 0, stream>>>(msk, mpk_b);

    u16* w_nq  = w_ip + 1769472;
    u16* w_out = w_nq + 589824;
    u16* w_fc  = w_out + 589824;
    u16* w_pj  = w_fc + 2359296;

    // x = LN1(y) -> bf16
    ln_kernel<<<2856, 256, 0, stream>>>(y, l1g, l1b, x_b, 11424);
    // qkv = x[100:] @ in_proj_w.T + b
    gemm_bt<0, 1, 0><<<dim3(65, 18), 256, 0, stream>>>(x_b + (size_t)3200 * 768, w_ip, ipb, nullptr, qkv_b, 8224, 2304, 768);
    // new_q = x[:100] @ new_q_w.T + b
    gemm_bt<0, 1, 0><<<dim3(25, 6), 256, 0, stream>>>(x_b, w_nq, nqb, nullptr, nq_b, 3200, 768, 768);
    // attention
    attn_kernel<<<384, 256, 0, stream>>>(qkv_b, nq_b, mpk_b, ao_b);
    // y2 = y + attn_out @ out_w.T + out_b   -> d_out (f32)
    gemm_bt<0, 0, 1><<<dim3(90, 6), 256, 0, stream>>>(ao_b, w_out, ob, y, out, 11424, 768, 768);
    // h = LN2(y2) -> bf16
    ln_kernel<<<2856, 256, 0, stream>>>(out, l2g, l2b, h_b, 11424);
    // h1 = quickgelu(h @ fc_w.T + fc_b) -> bf16
    gemm_bt<1, 1, 0><<<dim3(90, 24), 256, 0, stream>>>(h_b, w_fc, fcb, nullptr, h1_b, 11424, 3072, 768);
    // out = y2 + h1 @ proj_w.T + proj_b
    gemm_bt<0, 0, 1><<<dim3(90, 6), 256, 0, stream>>>(h1_b, w_pj, pjb, out, out, 11424, 768, 3072);
}

// Round 7
// 485.278 us; speedup vs baseline: 1.1591x; 1.0107x over previous
//
#include <hip/hip_runtime.h>

// ResidualAttentionBlock on MI355X (gfx950).
// D=768 H=12 HD=64 NQ=100 KV=257 SEQ=357 BS=32.
// Round 7: revert GEMM to R4 2-buffer prefetch (R6's counted-vmcnt regressed);
// add T1 bijective XCD swizzle to gemm_bt and b-grouping XCD swizzle to attn
// (FETCH_SIZE showed 5x L2-miss over-fetch from cross-XCD scatter).

typedef short bf16x8 __attribute__((ext_vector_type(8)));
typedef float f32x4 __attribute__((ext_vector_type(4)));
typedef unsigned short u16;
typedef unsigned long long u64;

__device__ __forceinline__ u16 f2b(float f) {
    unsigned u = __builtin_bit_cast(unsigned, f);
    u = (u + 0x7fffu + ((u >> 16) & 1u)) >> 16;  // RNE
    return (u16)u;
}
__device__ __forceinline__ float b2f(u16 h) {
    unsigned u = ((unsigned)h) << 16;
    return __builtin_bit_cast(float, u);
}
__device__ __forceinline__ unsigned pack2(float a, float b) {
    return (unsigned)f2b(a) | ((unsigned)f2b(b) << 16);
}
// async global->LDS, 16B per lane; LDS dest = wave-uniform base + lane*16
__device__ __forceinline__ void g2l16(const void* g, void* l) {
    __builtin_amdgcn_global_load_lds(
        (__attribute__((address_space(1))) void*)g,
        (__attribute__((address_space(3))) void*)l, 16, 0, 0);
}
#define MFMA16(a, b, c) __builtin_amdgcn_mfma_f32_16x16x32_bf16((a), (b), (c), 0, 0, 0)

// ---------------- fused f32 -> bf16 conversion of all 5 weights ----------------
__global__ __launch_bounds__(256) void cvt5_kernel(
    const float* __restrict__ s0, const float* __restrict__ s1, const float* __restrict__ s2,
    const float* __restrict__ s3, const float* __restrict__ s4, u16* __restrict__ dst)
{
    int i = blockIdx.x * 256 + threadIdx.x;
    int stride = gridDim.x * 256;
    for (; i < 1916928; i += stride) {
        const float* src; int off;
        if (i < 442368)       { src = s0; off = i; }
        else if (i < 589824)  { src = s1; off = i - 442368; }
        else if (i < 737280)  { src = s2; off = i - 589824; }
        else if (i < 1327104) { src = s3; off = i - 737280; }
        else                  { src = s4; off = i - 1327104; }
        float4 v = ((const float4*)src)[off];
        ushort4 o;
        o.x = f2b(v.x); o.y = f2b(v.y); o.z = f2b(v.z); o.w = f2b(v.w);
        ((ushort4*)dst)[i] = o;
    }
}

// ---------------- mask -> packed bitmask [32*100][5] u64 ----------------
__global__ __launch_bounds__(256) void mask_pack(const int* __restrict__ m, u64* __restrict__ o) {
    int row = blockIdx.x * 4 + (threadIdx.x >> 6);
    int lane = threadIdx.x & 63;
    if (row >= 3200) return;
    const int* r = m + (size_t)row * 257;
    u64 w0 = __ballot(r[lane] != 0);
    u64 w1 = __ballot(r[64 + lane] != 0);
    u64 w2 = __ballot(r[128 + lane] != 0);
    u64 w3 = __ballot(r[192 + lane] != 0);
    u64 w4 = __ballot(lane == 0 && r[256] != 0);
    if (lane == 0) {
        u64* p = o + (size_t)row * 5;
        p[0] = w0; p[1] = w1; p[2] = w2; p[3] = w3; p[4] = w4;
    }
}

// ---------------- LayerNorm (fp32 in, bf16 out), one wave per row of 768 ----------------
__global__ __launch_bounds__(256) void ln_kernel(
    const float* __restrict__ in, const float* __restrict__ g, const float* __restrict__ be,
    u16* __restrict__ out, int nrows)
{
    int row = blockIdx.x * 4 + (threadIdx.x >> 6);
    int lane = threadIdx.x & 63;
    if (row >= nrows) return;
    const float* p = in + (size_t)row * 768;
    float4 a0 = *(const float4*)(p + lane * 4);
    float4 a1 = *(const float4*)(p + 256 + lane * 4);
    float4 a2 = *(const float4*)(p + 512 + lane * 4);
    float s = a0.x + a0.y + a0.z + a0.w + a1.x + a1.y + a1.z + a1.w + a2.x + a2.y + a2.z + a2.w;
    for (int o = 32; o; o >>= 1) s += __shfl_xor(s, o);
    float mean = s * (1.f / 768.f);
    float vs = 0.f;
#define SQA(t) { float dx; dx = t.x-mean; vs += dx*dx; dx = t.y-mean; vs += dx*dx; dx = t.z-mean; vs += dx*dx; dx = t.w-mean; vs += dx*dx; }
    SQA(a0) SQA(a1) SQA(a2)
#undef SQA
    for (int o = 32; o; o >>= 1) vs += __shfl_xor(vs, o);
    float rstd = rsqrtf(vs * (1.f / 768.f) + 1e-5f);
    u16* orow = out + (size_t)row * 768;
#pragma unroll
    for (int i = 0; i < 3; ++i) {
        int d = i * 256 + lane * 4;
        float4 av = (i == 0) ? a0 : ((i == 1) ? a1 : a2);
        float4 gv = *(const float4*)(g + d);
        float4 bv = *(const float4*)(be + d);
        ushort4 ov;
        ov.x = f2b((av.x - mean) * rstd * gv.x + bv.x);
        ov.y = f2b((av.y - mean) * rstd * gv.y + bv.y);
        ov.z = f2b((av.z - mean) * rstd * gv.z + bv.z);
        ov.w = f2b((av.w - mean) * rstd * gv.w + bv.w);
        *(ushort4*)(orow + d) = ov;
    }
}

// ---------------- bf16 MFMA GEMM: C[M][N] = A[M][K] @ B[N][K]^T + bias (+res) ----------------
// 128x128 tile, 4 waves (2x2), 4x4 16x16 frags/wave, BK=32.
// 2-buffer LDS, prefetch-ahead staging, one barrier per K-step (R4 structure).
// T1: bijective XCD swizzle so consecutive blocks (shared B-panel) colocate per XCD.
template<int ACT, int OUTBF, int RES>
__global__ __launch_bounds__(256) void gemm_bt(
    const u16* __restrict__ A, const u16* __restrict__ B,
    const float* __restrict__ bias, const float* __restrict__ res,
    void* __restrict__ Cp, int M, int N, int K)
{
    __shared__ u16 Al[2][128 * 32];
    __shared__ u16 Bl[2][128 * 32];
    const int t = threadIdx.x;
    const int lane = t & 63, w = t >> 6;
    const int wr = w >> 1, wc = w & 1;
    const int fr = lane & 15, fg = lane >> 4;

    // T1 bijective XCD swizzle (m204): XCD k gets a contiguous range of linear ids.
    const int nwg = gridDim.x * gridDim.y;
    int orig = blockIdx.x + gridDim.x * blockIdx.y;
    {
        int q = nwg >> 3, r = nwg & 7;
        int xcd = orig & 7, idx = orig >> 3;
        orig = (xcd < r ? xcd * (q + 1) : r * (q + 1) + (xcd - r) * q) + idx;
    }
    const int m0 = (orig % gridDim.x) * 128;
    const int n0 = (orig / gridDim.x) * 128;

    // staging: wave w covers rows w*32..w*32+31 (2 instrs of 16 rows); lane l -> row +(l>>2),
    // 16B slot (l&3). LDS dest is wave-uniform base + lane*16; global src per-lane (row-clamped).
    const int srow = lane >> 2;
    const int scol = (lane & 3) * 8;
    int ar0 = m0 + w * 32 + srow;      int ar1 = ar0 + 16;
    ar0 = ar0 < M ? ar0 : M - 1;       ar1 = ar1 < M ? ar1 : M - 1;
    int br0 = n0 + w * 32 + srow;      int br1 = br0 + 16;
    br0 = br0 < N ? br0 : N - 1;       br1 = br1 < N ? br1 : N - 1;
    const u16* a0p = A + (size_t)ar0 * K + scol;
    const u16* a1p = A + (size_t)ar1 * K + scol;
    const u16* b0p = B + (size_t)br0 * K + scol;
    const u16* b1p = B + (size_t)br1 * K + scol;
    const int lo0 = (w * 2 + 0) * 512, lo1 = (w * 2 + 1) * 512;

    const int nk = K >> 5;
    g2l16(a0p, &Al[0][lo0]);
    g2l16(a1p, &Al[0][lo1]);
    g2l16(b0p, &Bl[0][lo0]);
    g2l16(b1p, &Bl[0][lo1]);
    __syncthreads();

    f32x4 acc[4][4] = {};
#pragma unroll 2
    for (int ki = 0; ki < nk; ++ki) {
        const int cur = ki & 1;
        if (ki + 1 < nk) {               // issue next-tile loads BEFORE compute
            const int k0 = (ki + 1) << 5;
            const int nxt = cur ^ 1;
            g2l16(a0p + k0, &Al[nxt][lo0]);
            g2l16(a1p + k0, &Al[nxt][lo1]);
            g2l16(b0p + k0, &Bl[nxt][lo0]);
            g2l16(b1p + k0, &Bl[nxt][lo1]);
        }
        bf16x8 af[4], bfr[4];
#pragma unroll
        for (int m = 0; m < 4; ++m) af[m] = *(const bf16x8*)&Al[cur][(wr * 64 + m * 16 + fr) * 32 + fg * 8];
#pragma unroll
        for (int n = 0; n < 4; ++n) bfr[n] = *(const bf16x8*)&Bl[cur][(wc * 64 + n * 16 + fr) * 32 + fg * 8];
#pragma unroll
        for (int m = 0; m < 4; ++m)
#pragma unroll
            for (int n = 0; n < 4; ++n)
                acc[m][n] = MFMA16(af[m], bfr[n], acc[m][n]);
        __syncthreads();  // drains this wave's vmcnt(0) (next-tile loads) + barrier
    }
    // Epilogue. C/D layout: col = lane&15, row = (lane>>4)*4 + r  [measured m89/m91]
#pragma unroll
    for (int m = 0; m < 4; ++m) {
#pragma unroll
        for (int n = 0; n < 4; ++n) {
            int col = n0 + wc * 64 + n * 16 + fr;
            float bv = bias[col];
#pragma unroll
            for (int r = 0; r < 4; ++r) {
                int row = m0 + wr * 64 + m * 16 + fg * 4 + r;
                if (row < M) {
                    float v = acc[m][n][r] + bv;
                    if (RES) v += res[(size_t)row * N + col];
                    if (ACT) v = v / (1.f + __expf(-1.702f * v));  // QuickGELU
                    if (OUTBF) ((u16*)Cp)[(size_t)row * N + col] = f2b(v);
                    else       ((float*)Cp)[(size_t)row * N + col] = v;
                }
            }
        }
    }
}

// ---------------- MFMA attention: one block per (b,h) ----------------
// XCD swizzle: raw blockIdx round-robins XCDs, so map raw -> bid such that each XCD's
// 48 blocks are CONTIGUOUS bids = 4 complete batches -> K/V reads become XCD-local L2 hits.
__global__ __launch_bounds__(256, 2) void attn_kernel(
    const u16* __restrict__ qkv,   // [257*32][2304] rows m*32+b; q|k|v at +0/+768/+1536
    const u16* __restrict__ nq,    // [100*32][768]  rows q*32+b
    const u64* __restrict__ mpk,   // [32*100][5] packed mask bits (1 = blocked)
    u16* __restrict__ out)         // [357*32][768]  rows q*32+b
{
    __shared__ u16 Kl[272 * 64];   // K rows, XOR-swizzled: byte ^= (row&7)<<4
    __shared__ u16 Vt[64 * 296];   // Vt[d][m], row stride 592B
    __shared__ u16 Pb[4][640];     // per-wave P chunk buffer [16][40]
    const int raw = blockIdx.x;
    const int bid = (raw & 7) * 48 + (raw >> 3);   // 384 = 8 XCDs x 48 contiguous
    const int b = bid / 12, h = bid % 12;
    const int t = threadIdx.x, lane = t & 63, wv = t >> 6;
    const int fr = lane & 15, fg = lane >> 4;

    for (int i = t; i < 2048; i += 256) {
        int d = i >> 5, c = 257 + (i & 31);
        if (c < 288) Vt[d * 296 + c] = 0;
    }
    {
        const int r8 = t >> 3, c8 = (t & 7) * 8;
        const u16* kb = qkv + 768 + h * 64 + c8;
        const u16* vb = qkv + 1536 + h * 64 + c8;
#pragma unroll 1
        for (int p = 0; p < 9; ++p) {
            int m = r8 + p * 32;
            if (m <= 256) {
                size_t go = (size_t)(m * 32 + b) * 2304;
                bf16x8 kv = *(const bf16x8*)(kb + go);
                int byte = m * 128 + c8 * 2;
                *(bf16x8*)((char*)Kl + (byte ^ ((m & 7) << 4))) = kv;
                bf16x8 vv = *(const bf16x8*)(vb + go);
#pragma unroll
                for (int j = 0; j < 8; ++j)
                    Vt[(c8 + j) * 296 + m] = (u16)vv[j];
            }
        }
    }
    __syncthreads();

    const int swzK = (fr & 7) << 4;
    char* pb = (char*)&Pb[wv][0];
    const char* KlB = (const char*)Kl;
    const char* VtB = (const char*)Vt;

    auto fetch = [&](int ti, bf16x8& q0v, bf16x8& q1v, u64* mw, bool& im) {
        int q = ti * 16 + fr;
        int qc = q < 357 ? q : 356;
        im = qc < 100;
        const u16* qp = im ? (nq + (size_t)(qc * 32 + b) * 768 + h * 64)
                           : (qkv + (size_t)((qc - 100) * 32 + b) * 2304 + h * 64);
        q0v = *(const bf16x8*)(qp + fg * 8);
        q1v = *(const bf16x8*)(qp + 32 + fg * 8);
        if (im) {
            const u64* mp = mpk + (size_t)(b * 100 + qc) * 5;
            mw[0] = mp[0]; mw[1] = mp[1]; mw[2] = mp[2]; mw[3] = mp[3]; mw[4] = mp[4];
        } else {
            mw[0] = mw[1] = mw[2] = mw[3] = mw[4] = 0;
        }
    };

    bf16x8 qf0, qf1, qn0, qn1;
    u64 mwc[5], mwn[5];
    bool imc, imn;
    fetch(wv, qf0, qf1, mwc, imc);

#pragma unroll 1
    for (int ti = wv; ti < 23; ti += 4) {
        f32x4 sc[17];
#pragma unroll
        for (int kt = 0; kt < 17; ++kt) {
            int rb = (kt * 16 + fr) * 128;
            bf16x8 ka0 = *(const bf16x8*)(KlB + ((rb + fg * 16) ^ swzK));
            bf16x8 ka1 = *(const bf16x8*)(KlB + ((rb + 64 + fg * 16) ^ swzK));
            f32x4 a = {0.f, 0.f, 0.f, 0.f};
            a = MFMA16(ka0, qf0, a);
            a = MFMA16(ka1, qf1, a);
            sc[kt] = a;
        }
        if (ti + 4 < 23) fetch(ti + 4, qn0, qn1, mwn, imn);
        float mx = -INFINITY;
#pragma unroll
        for (int kt = 0; kt < 17; ++kt) {
            u64 mw = (kt >> 2) == 0 ? mwc[0] : (kt >> 2) == 1 ? mwc[1] : (kt >> 2) == 2 ? mwc[2]
                   : (kt >> 2) == 3 ? mwc[3] : mwc[4];
#pragma unroll
            for (int r = 0; r < 4; ++r) {
                int key = kt * 16 + fg * 4 + r;
                bool bad = (key > 256) || (imc && ((mw >> (key & 63)) & 1ull));
                float s = bad ? -INFINITY : sc[kt][r];
                sc[kt][r] = s;
                mx = fmaxf(mx, s);
            }
        }
        mx = fmaxf(mx, __shfl_xor(mx, 16));
        mx = fmaxf(mx, __shfl_xor(mx, 32));
        float l = 0.f;
        unsigned pk[17][2];
#pragma unroll
        for (int kt = 0; kt < 17; ++kt) {
            float p0 = __expf((sc[kt][0] - mx) * 0.125f);
            float p1 = __expf((sc[kt][1] - mx) * 0.125f);
            float p2 = __expf((sc[kt][2] - mx) * 0.125f);
            float p3 = __expf((sc[kt][3] - mx) * 0.125f);
            l += (p0 + p1) + (p2 + p3);
            pk[kt][0] = pack2(p0, p1);
            pk[kt][1] = pack2(p2, p3);
        }
        l += __shfl_xor(l, 16);
        l += __shfl_xor(l, 32);
        f32x4 oc[4] = {};
#pragma unroll
        for (int c = 0; c < 9; ++c) {
            uint2 w0; w0.x = pk[2 * c][0]; w0.y = pk[2 * c][1];
            *(uint2*)(pb + fr * 80 + fg * 8) = w0;
            uint2 w1;
            if (c < 8) { w1.x = pk[2 * c + 1][0]; w1.y = pk[2 * c + 1][1]; }
            else       { w1.x = 0; w1.y = 0; }
            *(uint2*)(pb + fr * 80 + 32 + fg * 8) = w1;
            bf16x8 pf = *(const bf16x8*)(pb + fr * 80 + fg * 16);
#pragma unroll
            for (int dt = 0; dt < 4; ++dt) {
                bf16x8 vf = *(const bf16x8*)(VtB + (dt * 16 + fr) * 592 + c * 64 + fg * 16);
                oc[dt] = MFMA16(vf, pf, oc[dt]);
            }
        }
        int q = ti * 16 + fr;
        if (q < 357) {
            float rl = 1.f / l;
            u16* op = out + (size_t)(q * 32 + b) * 768 + h * 64 + fg * 4;
#pragma unroll
            for (int dt = 0; dt < 4; ++dt) {
                ushort4 ov;
                ov.x = f2b(oc[dt][0] * rl); ov.y = f2b(oc[dt][1] * rl);
                ov.z = f2b(oc[dt][2] * rl); ov.w = f2b(oc[dt][3] * rl);
                *(ushort4*)(op + dt * 16) = ov;
            }
        }
        if (ti + 4 < 23) {
            qf0 = qn0; qf1 = qn1; imc = imn;
            mwc[0] = mwn[0]; mwc[1] = mwn[1]; mwc[2] = mwn[2]; mwc[3] = mwn[3]; mwc[4] = mwn[4];
        }
    }
}

// ---------------- launch ----------------
extern "C" void kernel_launch(void* const* d_in, const int* in_sizes, int n_in,
                              void* d_out, int out_size, void* d_ws, size_t ws_size,
                              hipStream_t stream)
{
    const float* y   = (const float*)d_in[0];
    const int*   msk = (const int*)  d_in[1];
    const float* ipw = (const float*)d_in[2];
    const float* ipb = (const float*)d_in[3];
    const float* nqw = (const float*)d_in[4];
    const float* nqb = (const float*)d_in[5];
    const float* ow  = (const float*)d_in[6];
    const float* ob  = (const float*)d_in[7];
    const float* l1g = (const float*)d_in[8];
    const float* l1b = (const float*)d_in[9];
    const float* l2g = (const float*)d_in[10];
    const float* l2b = (const float*)d_in[11];
    const float* fcw = (const float*)d_in[12];
    const float* fcb = (const float*)d_in[13];
    const float* pjw = (const float*)d_in[14];
    const float* pjb = (const float*)d_in[15];

    char* ws = (char*)d_ws;
    u16* x_b   = (u16*)(ws + 0);          // 11424 x 768
    u16* qkv_b = (u16*)(ws + 17547264);   //  8224 x 2304
    u16* nq_b  = (u16*)(ws + 55443456);   //  3200 x 768
    u16* ao_b  = (u16*)(ws + 60358656);   // 11424 x 768
    u16* h1_b  = (u16*)(ws + 0);          // 11424 x 3072 (phase 2, overlaps phase-1 region)
    u16* h_b   = (u16*)(ws + 77905920);   // 11424 x 768 (phase 2)
    u64* mpk_b = (u64*)(ws + 77905920);   // 3200 x 5 u64 (phase 1 only)
    u16* w_ip  = (u16*)(ws + 95453184);   // weights contiguous: ip|nq|out|fc|pj
    float* out = (float*)d_out;

    cvt5_kernel<<<2048, 256, 0, stream>>>(ipw, nqw, ow, fcw, pjw, w_ip);
    mask_pack<<<800, 256, 0, stream>>>(msk, mpk_b);

    u16* w_nq  = w_ip + 1769472;
    u16* w_out = w_nq + 589824;
    u16* w_fc  = w_out + 589824;
    u16* w_pj  = w_fc + 2359296;

    // x = LN1(y) -> bf16
    ln_kernel<<<2856, 256, 0, stream>>>(y, l1g, l1b, x_b, 11424);
    // qkv = x[100:] @ in_proj_w.T + b
    gemm_bt<0, 1, 0><<<dim3(65, 18), 256, 0, stream>>>(x_b + (size_t)3200 * 768, w_ip, ipb, nullptr, qkv_b, 8224, 2304, 768);
    // new_q = x[:100] @ new_q_w.T + b
    gemm_bt<0, 1, 0><<<dim3(25, 6), 256, 0, stream>>>(x_b, w_nq, nqb, nullptr, nq_b, 3200, 768, 768);
    // attention
    attn_kernel<<<384, 256, 0, stream>>>(qkv_b, nq_b, mpk_b, ao_b);
    // y2 = y + attn_out @ out_w.T + out_b   -> d_out (f32)
    gemm_bt<0, 0, 1><<<dim3(90, 6), 256, 0, stream>>>(ao_b, w_out, ob, y, out, 11424, 768, 768);
    // h = LN2(y2) -> bf16
    ln_kernel<<<2856, 256, 0, stream>>>(out, l2g, l2b, h_b, 11424);
    // h1 = quickgelu(h @ fc_w.T + fc_b) -> bf16
    gemm_bt<1, 1, 0><<<dim3(90, 24), 256, 0, stream>>>(h_b, w_fc, fcb, nullptr, h1_b, 11424, 3072, 768);
    // out = y2 + h1 @ proj_w.T + proj_b
    gemm_bt<0, 0, 1><<<dim3(90, 6), 256, 0, stream>>>(h1_b, w_pj, pjb, out, out, 11424, 768, 3072);
}

// Round 8
// 449.161 us; speedup vs baseline: 1.2523x; 1.0804x over previous
//
#include <hip/hip_runtime.h>

// ResidualAttentionBlock on MI355X (gfx950).
// D=768 H=12 HD=64 NQ=100 KV=257 SEQ=357 BS=32.
// Round 8: GEMM XCD mapping fixed -> A-row-slice per XCD, column-inner traversal
// (R7's column-chunk swizzle re-streamed full A per column: FETCH 178->229 MB regression).
// GEMM pipeline structure = R4 2-buffer prefetch (best measured). Attn swizzle kept.

typedef short bf16x8 __attribute__((ext_vector_type(8)));
typedef float f32x4 __attribute__((ext_vector_type(4)));
typedef unsigned short u16;
typedef unsigned long long u64;

__device__ __forceinline__ u16 f2b(float f) {
    unsigned u = __builtin_bit_cast(unsigned, f);
    u = (u + 0x7fffu + ((u >> 16) & 1u)) >> 16;  // RNE
    return (u16)u;
}
__device__ __forceinline__ float b2f(u16 h) {
    unsigned u = ((unsigned)h) << 16;
    return __builtin_bit_cast(float, u);
}
__device__ __forceinline__ unsigned pack2(float a, float b) {
    return (unsigned)f2b(a) | ((unsigned)f2b(b) << 16);
}
// async global->LDS, 16B per lane; LDS dest = wave-uniform base + lane*16
__device__ __forceinline__ void g2l16(const void* g, void* l) {
    __builtin_amdgcn_global_load_lds(
        (__attribute__((address_space(1))) void*)g,
        (__attribute__((address_space(3))) void*)l, 16, 0, 0);
}
#define MFMA16(a, b, c) __builtin_amdgcn_mfma_f32_16x16x32_bf16((a), (b), (c), 0, 0, 0)

// ---------------- fused f32 -> bf16 conversion of all 5 weights ----------------
__global__ __launch_bounds__(256) void cvt5_kernel(
    const float* __restrict__ s0, const float* __restrict__ s1, const float* __restrict__ s2,
    const float* __restrict__ s3, const float* __restrict__ s4, u16* __restrict__ dst)
{
    int i = blockIdx.x * 256 + threadIdx.x;
    int stride = gridDim.x * 256;
    for (; i < 1916928; i += stride) {
        const float* src; int off;
        if (i < 442368)       { src = s0; off = i; }
        else if (i < 589824)  { src = s1; off = i - 442368; }
        else if (i < 737280)  { src = s2; off = i - 589824; }
        else if (i < 1327104) { src = s3; off = i - 737280; }
        else                  { src = s4; off = i - 1327104; }
        float4 v = ((const float4*)src)[off];
        ushort4 o;
        o.x = f2b(v.x); o.y = f2b(v.y); o.z = f2b(v.z); o.w = f2b(v.w);
        ((ushort4*)dst)[i] = o;
    }
}

// ---------------- mask -> packed bitmask [32*100][5] u64 ----------------
__global__ __launch_bounds__(256) void mask_pack(const int* __restrict__ m, u64* __restrict__ o) {
    int row = blockIdx.x * 4 + (threadIdx.x >> 6);
    int lane = threadIdx.x & 63;
    if (row >= 3200) return;
    const int* r = m + (size_t)row * 257;
    u64 w0 = __ballot(r[lane] != 0);
    u64 w1 = __ballot(r[64 + lane] != 0);
    u64 w2 = __ballot(r[128 + lane] != 0);
    u64 w3 = __ballot(r[192 + lane] != 0);
    u64 w4 = __ballot(lane == 0 && r[256] != 0);
    if (lane == 0) {
        u64* p = o + (size_t)row * 5;
        p[0] = w0; p[1] = w1; p[2] = w2; p[3] = w3; p[4] = w4;
    }
}

// ---------------- LayerNorm (fp32 in, bf16 out), one wave per row of 768 ----------------
__global__ __launch_bounds__(256) void ln_kernel(
    const float* __restrict__ in, const float* __restrict__ g, const float* __restrict__ be,
    u16* __restrict__ out, int nrows)
{
    int row = blockIdx.x * 4 + (threadIdx.x >> 6);
    int lane = threadIdx.x & 63;
    if (row >= nrows) return;
    const float* p = in + (size_t)row * 768;
    float4 a0 = *(const float4*)(p + lane * 4);
    float4 a1 = *(const float4*)(p + 256 + lane * 4);
    float4 a2 = *(const float4*)(p + 512 + lane * 4);
    float s = a0.x + a0.y + a0.z + a0.w + a1.x + a1.y + a1.z + a1.w + a2.x + a2.y + a2.z + a2.w;
    for (int o = 32; o; o >>= 1) s += __shfl_xor(s, o);
    float mean = s * (1.f / 768.f);
    float vs = 0.f;
#define SQA(t) { float dx; dx = t.x-mean; vs += dx*dx; dx = t.y-mean; vs += dx*dx; dx = t.z-mean; vs += dx*dx; dx = t.w-mean; vs += dx*dx; }
    SQA(a0) SQA(a1) SQA(a2)
#undef SQA
    for (int o = 32; o; o >>= 1) vs += __shfl_xor(vs, o);
    float rstd = rsqrtf(vs * (1.f / 768.f) + 1e-5f);
    u16* orow = out + (size_t)row * 768;
#pragma unroll
    for (int i = 0; i < 3; ++i) {
        int d = i * 256 + lane * 4;
        float4 av = (i == 0) ? a0 : ((i == 1) ? a1 : a2);
        float4 gv = *(const float4*)(g + d);
        float4 bv = *(const float4*)(be + d);
        ushort4 ov;
        ov.x = f2b((av.x - mean) * rstd * gv.x + bv.x);
        ov.y = f2b((av.y - mean) * rstd * gv.y + bv.y);
        ov.z = f2b((av.z - mean) * rstd * gv.z + bv.z);
        ov.w = f2b((av.w - mean) * rstd * gv.w + bv.w);
        *(ushort4*)(orow + d) = ov;
    }
}

// ---------------- bf16 MFMA GEMM: C[M][N] = A[M][K] @ B[N][K]^T + bias (+res) ----------------
// 128x128 tile, 4 waves (2x2), 4x4 16x16 frags/wave, BK=32.
// 2-buffer LDS, prefetch-ahead staging, one barrier per K-step (R4 structure).
// XCD mapping: gridDim.x padded to x8; XCD k owns M-tile slice [k*gx/8, (k+1)*gx/8),
// column-inner order -> A-slice L2-resident, B panels cycle.
template<int ACT, int OUTBF, int RES>
__global__ __launch_bounds__(256) void gemm_bt(
    const u16* __restrict__ A, const u16* __restrict__ B,
    const float* __restrict__ bias, const float* __restrict__ res,
    void* __restrict__ Cp, int M, int N, int K)
{
    __shared__ u16 Al[2][128 * 32];
    __shared__ u16 Bl[2][128 * 32];
    const int t = threadIdx.x;
    const int lane = t & 63, w = t >> 6;
    const int wr = w >> 1, wc = w & 1;
    const int fr = lane & 15, fg = lane >> 4;

    // A-row-slice per XCD (raw%8 -> XCD heuristic), column-inner within slice.
    const int raw = blockIdx.x + gridDim.x * blockIdx.y;
    const int rows_per = gridDim.x >> 3;          // gridDim.x % 8 == 0
    const int gy = gridDim.y;
    const int xcd = raw & 7, idx = raw >> 3;
    const int nt = idx % gy;
    const int mt = xcd * rows_per + idx / gy;
    const int m0 = mt * 128, n0 = nt * 128;
    if (m0 >= M) return;                          // padded tail block (uniform exit, pre-barrier)

    // staging: wave w covers rows w*32..w*32+31 (2 instrs of 16 rows); lane l -> row +(l>>2),
    // 16B slot (l&3). LDS dest is wave-uniform base + lane*16; global src per-lane (row-clamped).
    const int srow = lane >> 2;
    const int scol = (lane & 3) * 8;
    int ar0 = m0 + w * 32 + srow;      int ar1 = ar0 + 16;
    ar0 = ar0 < M ? ar0 : M - 1;       ar1 = ar1 < M ? ar1 : M - 1;
    int br0 = n0 + w * 32 + srow;      int br1 = br0 + 16;
    br0 = br0 < N ? br0 : N - 1;       br1 = br1 < N ? br1 : N - 1;
    const u16* a0p = A + (size_t)ar0 * K + scol;
    const u16* a1p = A + (size_t)ar1 * K + scol;
    const u16* b0p = B + (size_t)br0 * K + scol;
    const u16* b1p = B + (size_t)br1 * K + scol;
    const int lo0 = (w * 2 + 0) * 512, lo1 = (w * 2 + 1) * 512;

    const int nk = K >> 5;
    g2l16(a0p, &Al[0][lo0]);
    g2l16(a1p, &Al[0][lo1]);
    g2l16(b0p, &Bl[0][lo0]);
    g2l16(b1p, &Bl[0][lo1]);
    __syncthreads();

    f32x4 acc[4][4] = {};
#pragma unroll 2
    for (int ki = 0; ki < nk; ++ki) {
        const int cur = ki & 1;
        if (ki + 1 < nk) {               // issue next-tile loads BEFORE compute
            const int k0 = (ki + 1) << 5;
            const int nxt = cur ^ 1;
            g2l16(a0p + k0, &Al[nxt][lo0]);
            g2l16(a1p + k0, &Al[nxt][lo1]);
            g2l16(b0p + k0, &Bl[nxt][lo0]);
            g2l16(b1p + k0, &Bl[nxt][lo1]);
        }
        bf16x8 af[4], bfr[4];
#pragma unroll
        for (int m = 0; m < 4; ++m) af[m] = *(const bf16x8*)&Al[cur][(wr * 64 + m * 16 + fr) * 32 + fg * 8];
#pragma unroll
        for (int n = 0; n < 4; ++n) bfr[n] = *(const bf16x8*)&Bl[cur][(wc * 64 + n * 16 + fr) * 32 + fg * 8];
#pragma unroll
        for (int m = 0; m < 4; ++m)
#pragma unroll
            for (int n = 0; n < 4; ++n)
                acc[m][n] = MFMA16(af[m], bfr[n], acc[m][n]);
        __syncthreads();  // drains this wave's vmcnt(0) (next-tile loads) + barrier
    }
    // Epilogue. C/D layout: col = lane&15, row = (lane>>4)*4 + r  [measured m89/m91]
#pragma unroll
    for (int m = 0; m < 4; ++m) {
#pragma unroll
        for (int n = 0; n < 4; ++n) {
            int col = n0 + wc * 64 + n * 16 + fr;
            float bv = bias[col];
#pragma unroll
            for (int r = 0; r < 4; ++r) {
                int row = m0 + wr * 64 + m * 16 + fg * 4 + r;
                if (row < M) {
                    float v = acc[m][n][r] + bv;
                    if (RES) v += res[(size_t)row * N + col];
                    if (ACT) v = v / (1.f + __expf(-1.702f * v));  // QuickGELU
                    if (OUTBF) ((u16*)Cp)[(size_t)row * N + col] = f2b(v);
                    else       ((float*)Cp)[(size_t)row * N + col] = v;
                }
            }
        }
    }
}

// ---------------- MFMA attention: one block per (b,h) ----------------
// XCD swizzle: each XCD's 48 blocks contiguous = 4 complete batches -> K/V L2-local.
__global__ __launch_bounds__(256, 2) void attn_kernel(
    const u16* __restrict__ qkv,   // [257*32][2304] rows m*32+b; q|k|v at +0/+768/+1536
    const u16* __restrict__ nq,    // [100*32][768]  rows q*32+b
    const u64* __restrict__ mpk,   // [32*100][5] packed mask bits (1 = blocked)
    u16* __restrict__ out)         // [357*32][768]  rows q*32+b
{
    __shared__ u16 Kl[272 * 64];   // K rows, XOR-swizzled: byte ^= (row&7)<<4
    __shared__ u16 Vt[64 * 296];   // Vt[d][m], row stride 592B
    __shared__ u16 Pb[4][640];     // per-wave P chunk buffer [16][40]
    const int raw = blockIdx.x;
    const int bid = (raw & 7) * 48 + (raw >> 3);   // 384 = 8 XCDs x 48 contiguous
    const int b = bid / 12, h = bid % 12;
    const int t = threadIdx.x, lane = t & 63, wv = t >> 6;
    const int fr = lane & 15, fg = lane >> 4;

    for (int i = t; i < 2048; i += 256) {
        int d = i >> 5, c = 257 + (i & 31);
        if (c < 288) Vt[d * 296 + c] = 0;
    }
    {
        const int r8 = t >> 3, c8 = (t & 7) * 8;
        const u16* kb = qkv + 768 + h * 64 + c8;
        const u16* vb = qkv + 1536 + h * 64 + c8;
#pragma unroll 1
        for (int p = 0; p < 9; ++p) {
            int m = r8 + p * 32;
            if (m <= 256) {
                size_t go = (size_t)(m * 32 + b) * 2304;
                bf16x8 kv = *(const bf16x8*)(kb + go);
                int byte = m * 128 + c8 * 2;
                *(bf16x8*)((char*)Kl + (byte ^ ((m & 7) << 4))) = kv;
                bf16x8 vv = *(const bf16x8*)(vb + go);
#pragma unroll
                for (int j = 0; j < 8; ++j)
                    Vt[(c8 + j) * 296 + m] = (u16)vv[j];
            }
        }
    }
    __syncthreads();

    const int swzK = (fr & 7) << 4;
    char* pb = (char*)&Pb[wv][0];
    const char* KlB = (const char*)Kl;
    const char* VtB = (const char*)Vt;

    auto fetch = [&](int ti, bf16x8& q0v, bf16x8& q1v, u64* mw, bool& im) {
        int q = ti * 16 + fr;
        int qc = q < 357 ? q : 356;
        im = qc < 100;
        const u16* qp = im ? (nq + (size_t)(qc * 32 + b) * 768 + h * 64)
                           : (qkv + (size_t)((qc - 100) * 32 + b) * 2304 + h * 64);
        q0v = *(const bf16x8*)(qp + fg * 8);
        q1v = *(const bf16x8*)(qp + 32 + fg * 8);
        if (im) {
            const u64* mp = mpk + (size_t)(b * 100 + qc) * 5;
            mw[0] = mp[0]; mw[1] = mp[1]; mw[2] = mp[2]; mw[3] = mp[3]; mw[4] = mp[4];
        } else {
            mw[0] = mw[1] = mw[2] = mw[3] = mw[4] = 0;
        }
    };

    bf16x8 qf0, qf1, qn0, qn1;
    u64 mwc[5], mwn[5];
    bool imc, imn;
    fetch(wv, qf0, qf1, mwc, imc);

#pragma unroll 1
    for (int ti = wv; ti < 23; ti += 4) {
        f32x4 sc[17];
#pragma unroll
        for (int kt = 0; kt < 17; ++kt) {
            int rb = (kt * 16 + fr) * 128;
            bf16x8 ka0 = *(const bf16x8*)(KlB + ((rb + fg * 16) ^ swzK));
            bf16x8 ka1 = *(const bf16x8*)(KlB + ((rb + 64 + fg * 16) ^ swzK));
            f32x4 a = {0.f, 0.f, 0.f, 0.f};
            a = MFMA16(ka0, qf0, a);
            a = MFMA16(ka1, qf1, a);
            sc[kt] = a;
        }
        if (ti + 4 < 23) fetch(ti + 4, qn0, qn1, mwn, imn);
        float mx = -INFINITY;
#pragma unroll
        for (int kt = 0; kt < 17; ++kt) {
            u64 mw = (kt >> 2) == 0 ? mwc[0] : (kt >> 2) == 1 ? mwc[1] : (kt >> 2) == 2 ? mwc[2]
                   : (kt >> 2) == 3 ? mwc[3] : mwc[4];
#pragma unroll
            for (int r = 0; r < 4; ++r) {
                int key = kt * 16 + fg * 4 + r;
                bool bad = (key > 256) || (imc && ((mw >> (key & 63)) & 1ull));
                float s = bad ? -INFINITY : sc[kt][r];
                sc[kt][r] = s;
                mx = fmaxf(mx, s);
            }
        }
        mx = fmaxf(mx, __shfl_xor(mx, 16));
        mx = fmaxf(mx, __shfl_xor(mx, 32));
        float l = 0.f;
        unsigned pk[17][2];
#pragma unroll
        for (int kt = 0; kt < 17; ++kt) {
            float p0 = __expf((sc[kt][0] - mx) * 0.125f);
            float p1 = __expf((sc[kt][1] - mx) * 0.125f);
            float p2 = __expf((sc[kt][2] - mx) * 0.125f);
            float p3 = __expf((sc[kt][3] - mx) * 0.125f);
            l += (p0 + p1) + (p2 + p3);
            pk[kt][0] = pack2(p0, p1);
            pk[kt][1] = pack2(p2, p3);
        }
        l += __shfl_xor(l, 16);
        l += __shfl_xor(l, 32);
        f32x4 oc[4] = {};
#pragma unroll
        for (int c = 0; c < 9; ++c) {
            uint2 w0; w0.x = pk[2 * c][0]; w0.y = pk[2 * c][1];
            *(uint2*)(pb + fr * 80 + fg * 8) = w0;
            uint2 w1;
            if (c < 8) { w1.x = pk[2 * c + 1][0]; w1.y = pk[2 * c + 1][1]; }
            else       { w1.x = 0; w1.y = 0; }
            *(uint2*)(pb + fr * 80 + 32 + fg * 8) = w1;
            bf16x8 pf = *(const bf16x8*)(pb + fr * 80 + fg * 16);
#pragma unroll
            for (int dt = 0; dt < 4; ++dt) {
                bf16x8 vf = *(const bf16x8*)(VtB + (dt * 16 + fr) * 592 + c * 64 + fg * 16);
                oc[dt] = MFMA16(vf, pf, oc[dt]);
            }
        }
        int q = ti * 16 + fr;
        if (q < 357) {
            float rl = 1.f / l;
            u16* op = out + (size_t)(q * 32 + b) * 768 + h * 64 + fg * 4;
#pragma unroll
            for (int dt = 0; dt < 4; ++dt) {
                ushort4 ov;
                ov.x = f2b(oc[dt][0] * rl); ov.y = f2b(oc[dt][1] * rl);
                ov.z = f2b(oc[dt][2] * rl); ov.w = f2b(oc[dt][3] * rl);
                *(ushort4*)(op + dt * 16) = ov;
            }
        }
        if (ti + 4 < 23) {
            qf0 = qn0; qf1 = qn1; imc = imn;
            mwc[0] = mwn[0]; mwc[1] = mwn[1]; mwc[2] = mwn[2]; mwc[3] = mwn[3]; mwc[4] = mwn[4];
        }
    }
}

// ---------------- launch ----------------
extern "C" void kernel_launch(void* const* d_in, const int* in_sizes, int n_in,
                              void* d_out, int out_size, void* d_ws, size_t ws_size,
                              hipStream_t stream)
{
    const float* y   = (const float*)d_in[0];
    const int*   msk = (const int*)  d_in[1];
    const float* ipw = (const float*)d_in[2];
    const float* ipb = (const float*)d_in[3];
    const float* nqw = (const float*)d_in[4];
    const float* nqb = (const float*)d_in[5];
    const float* ow  = (const float*)d_in[6];
    const float* ob  = (const float*)d_in[7];
    const float* l1g = (const float*)d_in[8];
    const float* l1b = (const float*)d_in[9];
    const float* l2g = (const float*)d_in[10];
    const float* l2b = (const float*)d_in[11];
    const float* fcw = (const float*)d_in[12];
    const float* fcb = (const float*)d_in[13];
    const float* pjw = (const float*)d_in[14];
    const float* pjb = (const float*)d_in[15];

    char* ws = (char*)d_ws;
    u16* x_b   = (u16*)(ws + 0);          // 11424 x 768
    u16* qkv_b = (u16*)(ws + 17547264);   //  8224 x 2304
    u16* nq_b  = (u16*)(ws + 55443456);   //  3200 x 768
    u16* ao_b  = (u16*)(ws + 60358656);   // 11424 x 768
    u16* h1_b  = (u16*)(ws + 0);          // 11424 x 3072 (phase 2, overlaps phase-1 region)
    u16* h_b   = (u16*)(ws + 77905920);   // 11424 x 768 (phase 2)
    u64* mpk_b = (u64*)(ws + 77905920);   // 3200 x 5 u64 (phase 1 only)
    u16* w_ip  = (u16*)(ws + 95453184);   // weights contiguous: ip|nq|out|fc|pj
    float* out = (float*)d_out;

    cvt5_kernel<<<2048, 256, 0, stream>>>(ipw, nqw, ow, fcw, pjw, w_ip);
    mask_pack<<<800, 256, 0, stream>>>(msk, mpk_b);

    u16* w_nq  = w_ip + 1769472;
    u16* w_out = w_nq + 589824;
    u16* w_fc  = w_out + 589824;
    u16* w_pj  = w_fc + 2359296;

    // x = LN1(y) -> bf16
    ln_kernel<<<2856, 256, 0, stream>>>(y, l1g, l1b, x_b, 11424);
    // qkv = x[100:] @ in_proj_w.T + b   (65 m-tiles -> pad gx to 72)
    gemm_bt<0, 1, 0><<<dim3(72, 18), 256, 0, stream>>>(x_b + (size_t)3200 * 768, w_ip, ipb, nullptr, qkv_b, 8224, 2304, 768);
    // new_q = x[:100] @ new_q_w.T + b   (25 -> 32)
    gemm_bt<0, 1, 0><<<dim3(32, 6), 256, 0, stream>>>(x_b, w_nq, nqb, nullptr, nq_b, 3200, 768, 768);
    // attention
    attn_kernel<<<384, 256, 0, stream>>>(qkv_b, nq_b, mpk_b, ao_b);
    // y2 = y + attn_out @ out_w.T + out_b   -> d_out (f32)   (90 -> 96)
    gemm_bt<0, 0, 1><<<dim3(96, 6), 256, 0, stream>>>(ao_b, w_out, ob, y, out, 11424, 768, 768);
    // h = LN2(y2) -> bf16
    ln_kernel<<<2856, 256, 0, stream>>>(out, l2g, l2b, h_b, 11424);
    // h1 = quickgelu(h @ fc_w.T + fc_b) -> bf16   (90 -> 96)
    gemm_bt<1, 1, 0><<<dim3(96, 24), 256, 0, stream>>>(h_b, w_fc, fcb, nullptr, h1_b, 11424, 3072, 768);
    // out = y2 + h1 @ proj_w.T + proj_b   (90 -> 96)
    gemm_bt<0, 0, 1><<<dim3(96, 6), 256, 0, stream>>>(h1_b, w_pj, pjb, out, out, 11424, 768, 3072);
}